// Round 9
// baseline (246.727 us; speedup 1.0000x reference)
//
#include <hip/hip_runtime.h>
#include <math.h>

// T5Attention forward, MI355X/gfx950.  Round 9:
//   prep_all (x+weights f32->f16, mask bitmask/bias)
//   fused QKV GEMM (N=3072, XCD-clustered grid), V TRANSPOSED [B][H][64][S];
//     Q pre-scaled 0.125*log2e (softmax in log2 domain)
//   flash attn: round-7 structure (KVBLK=128, swizzled global_load_lds dbuf,
//     prefetch-at-top + __syncthreads, swapped QK^T, defer-max, setprio,
//     XCD clustering) + exp2-domain softmax; VGPR pinned <=128
//   output GEMM 64x128 (XCD-clustered), f32 out

typedef float    f32x4 __attribute__((ext_vector_type(4)));
typedef _Float16 f16x8 __attribute__((ext_vector_type(8)));
typedef _Float16 f16x4 __attribute__((ext_vector_type(4)));

#define GLD16(gp, lp) __builtin_amdgcn_global_load_lds(                       \
    (const __attribute__((address_space(1))) void*)(gp),                      \
    (__attribute__((address_space(3))) void*)(lp), 16, 0, 0)

static constexpr int kB   = 2;
static constexpr int kS   = 2048;
static constexpr int kHID = 1024;
static constexpr int kH   = 16;
static constexpr float kLog2e = 1.44269504f;

// ------------------------------------------------------------ prep (fused) --
__global__ __launch_bounds__(256) void prep_all(const float* __restrict__ x,
                                                const float* __restrict__ w0,
                                                const float* __restrict__ w1,
                                                const float* __restrict__ w2,
                                                const float* __restrict__ w3,
                                                const int* __restrict__ maskp,
                                                _Float16* __restrict__ xh,
                                                _Float16* __restrict__ wh,
                                                float* __restrict__ maskbias,
                                                unsigned int* __restrict__ tileflags) {
  const int bid = blockIdx.x, tid = threadIdx.x;
  if (bid < 2048) {
    const float* src;
    _Float16* dst;
    int base;
    if (bid < 1024) {
      src = x; dst = xh; base = bid * 4096;
    } else {
      const int wsel = (bid - 1024) >> 8;
      src = wsel == 0 ? w0 : wsel == 1 ? w1 : wsel == 2 ? w2 : w3;
      dst = wh + (long)wsel * 1048576;
      base = ((bid - 1024) & 255) * 4096;
    }
#pragma unroll
    for (int it = 0; it < 4; ++it) {
      const int i = base + it * 1024 + tid * 4;
      const float4 v = *reinterpret_cast<const float4*>(src + i);
      f16x4 o;
      o[0] = (_Float16)v.x; o[1] = (_Float16)v.y;
      o[2] = (_Float16)v.z; o[3] = (_Float16)v.w;
      *reinterpret_cast<f16x4*>(dst + i) = o;
    }
  } else {
    const int b = bid - 2048;
    const int wave = tid >> 6, lane = tid & 63;
    __shared__ unsigned int partial[4];
    unsigned int mybits = 0;
#pragma unroll
    for (int it = 0; it < 8; ++it) {
      const int t = it * 4 + wave;
      const int kp = t * 64 + lane;
      const int mv = maskp[b * kS + kp];
      maskbias[b * kS + kp] = mv ? 0.f : -INFINITY;
      const unsigned long long bal = __ballot(mv != 0);
      if (bal == ~0ull) mybits |= (1u << t);
    }
    if (lane == 0) partial[wave] = mybits;
    __syncthreads();
    if (tid == 0) tileflags[b] = partial[0] | partial[1] | partial[2] | partial[3];
  }
}

// ------------------------------------------------------- fused QKV GEMM ----
// 1D grid 768, XCD-clustered: xcd x=bid&7 owns bx in [x*3,x*3+3) (B-panel
// 768KB resident per XCD L2); by = l%32 streams A.
__global__ __launch_bounds__(256) void gemm_qkv(const _Float16* __restrict__ A,
                                                const _Float16* __restrict__ W,
                                                _Float16* __restrict__ Qh,
                                                _Float16* __restrict__ Kh,
                                                _Float16* __restrict__ Vtg) {
  constexpr int K = kHID;
  __shared__ __align__(16) _Float16 As[128 * 32];
  __shared__ __align__(16) _Float16 Bs[128 * 32];
  const int tid  = threadIdx.x;
  const int lane = tid & 63;
  const int wave = tid >> 6;
  const int xcd = blockIdx.x & 7, l = blockIdx.x >> 3;
  const long bm = (long)(l & 31) * 128;             // by = l%32
  const long bn = (long)(xcd * 3 + (l >> 5)) * 128; // bx = xcd*3 + l/32
  const int wr = (wave >> 1) * 64;
  const int wc = (wave & 1) * 64;

  const int srow = wave * 32 + (lane >> 2);
  const int scol = (lane & 3) * 8;
  const _Float16* ga = A + (bm + srow) * (long)K + scol;
  const _Float16* gb = W + (bn + srow) * (long)K + scol;
  _Float16* lA0 = &As[wave * 1024];
  _Float16* lA1 = &As[wave * 1024 + 512];
  _Float16* lB0 = &Bs[wave * 1024];
  _Float16* lB1 = &Bs[wave * 1024 + 512];

  const int lr = lane & 15;
  const int lk = (lane >> 4) * 8;
  f32x4 acc[4][4] = {};

  for (int k0 = 0; k0 < K; k0 += 32) {
    GLD16(ga + k0, lA0);
    GLD16(ga + k0 + 16 * (long)K, lA1);
    GLD16(gb + k0, lB0);
    GLD16(gb + k0 + 16 * (long)K, lB1);
    __syncthreads();
    f16x8 af[4], bf[4];
#pragma unroll
    for (int i = 0; i < 4; ++i) {
      af[i] = *reinterpret_cast<const f16x8*>(&As[(wr + i * 16 + lr) * 32 + lk]);
      bf[i] = *reinterpret_cast<const f16x8*>(&Bs[(wc + i * 16 + lr) * 32 + lk]);
    }
#pragma unroll
    for (int i = 0; i < 4; ++i)
#pragma unroll
      for (int j = 0; j < 4; ++j)
        acc[i][j] = __builtin_amdgcn_mfma_f32_16x16x32_f16(af[i], bf[j], acc[i][j], 0, 0, 0);
    __syncthreads();
  }

  const int cr0 = wr + (lane >> 4) * 4;
  const int cc0 = wc + lr;
  const int cb = (int)(bn >> 10);          // 0=Q 1=K 2=V (block-uniform)
#pragma unroll
  for (int i = 0; i < 4; ++i)
#pragma unroll
    for (int j = 0; j < 4; ++j)
#pragma unroll
      for (int r = 0; r < 4; ++r) {
        const long row = bm + cr0 + i * 16 + r;       // token index
        const int  col = (int)bn + cc0 + j * 16;      // 0..3071
        const float v = acc[i][j][r];
        if (cb == 0) {
          // 1/sqrt(dk) * log2(e): softmax runs in log2 domain
          Qh[row * kHID + col] = (_Float16)(v * (0.125f * kLog2e));
        } else if (cb == 1) {
          Kh[row * kHID + (col - 1024)] = (_Float16)v;
        } else {
          const int hid = col - 2048;
          const int hh = hid >> 6, dd = hid & 63;
          const int bb = (int)(row >> 11), sp = (int)(row & 2047);
          Vtg[((long)(bb * kH + hh) * 64 + dd) * kS + sp] = (_Float16)v;
        }
      }
}

// ---------------------------------------------------------- flash attention -
// Round-7 structure (proven 57.6us) + log2-domain softmax.  1D grid 512,
// block 256, KVBLK=128, XCD-clustered, q-pairs {i,31-i}.  Prefetch at tile
// top, __syncthreads at tile end.  VGPR pinned <=128 (m69 cliff).
__global__ __launch_bounds__(256, 4) void attn_fwd6(const _Float16* __restrict__ Qh,
                                                    const _Float16* __restrict__ Kh,
                                                    const _Float16* __restrict__ Vtg,
                                                    const float* __restrict__ maskbias,
                                                    const unsigned int* __restrict__ tileflags,
                                                    const float* __restrict__ rel_emb,
                                                    _Float16* __restrict__ ctx) {
  __shared__ __align__(16) _Float16 Kt[2][128 * 64];
  __shared__ __align__(16) _Float16 Vt[2][64 * 128];
  __shared__ float bias_sh[32];

  const int tid  = threadIdx.x;
  const int lane = tid & 63;
  const int wave = tid >> 6;
  const int o = blockIdx.x;
  const int slot = o >> 3;
  const int p_ = (o & 7) + 8 * (slot >> 4);   // (b,h) group 0..31
  const int qp = slot & 15;                   // q pair 0..15
  const int b = p_ >> 4, h = p_ & 15;

  const int lr = lane & 15;
  const int lh = lane >> 4;

  if (tid < 32) bias_sh[tid] = rel_emb[tid * kH + h] * kLog2e;
  const unsigned int flags = tileflags[b];

  // K staging (inst t=0..3): lane l -> LDS row wave*32+t*8+(l>>3), chunk l&7.
  const int kro = wave * 32 + (lane >> 3);
  const int kch = ((lane & 7) ^ (lane >> 3)) * 8;
  const _Float16* ksrcT[4];
#pragma unroll
  for (int t = 0; t < 4; ++t)
    ksrcT[t] = Kh + ((long)b * kS + kro + t * 8) * kHID + h * 64 + kch;
  // V staging (inst t=0..3): lane l -> LDS row wave*16+t*4+(l>>4), chunk l&15.
  const long bh64 = (long)(b * kH + h) * 64;
  const _Float16* vsrcT[4];
#pragma unroll
  for (int t = 0; t < 4; ++t) {
    const int d = wave * 16 + t * 4 + (lane >> 4);
    const int c = (lane & 15) ^ (d & 15);
    vsrcT[t] = Vtg + (bh64 + d) * kS + c * 8;
  }

  __syncthreads();  // bias_sh visible before first use

  for (int pass = 0; pass < 2; ++pass) {
    const int qt = (pass == 0) ? qp : 31 - qp;
    const int qbase = qt * 64;

    const long qrow = (long)b * kS + qbase + wave * 16 + lr;
    const f16x8 qf0 = *reinterpret_cast<const f16x8*>(&Qh[qrow * kHID + h * 64 + lh * 8]);
    const f16x8 qf1 = *reinterpret_cast<const f16x8*>(&Qh[qrow * kHID + h * 64 + 32 + lh * 8]);

    float m = -INFINITY, lsum = 0.f;
    f32x4 acco[4] = {};

    // prologue: stage tile 0 -> buf 0
#pragma unroll
    for (int t = 0; t < 4; ++t) {
      GLD16(ksrcT[t], &Kt[0][wave * 2048 + t * 512]);
      GLD16(vsrcT[t], &Vt[0][wave * 2048 + t * 512]);
    }
    __syncthreads();

    const int ntiles = (qt >> 1) + 1;
    for (int kt = 0; kt < ntiles; ++kt) {
      const int cur = kt & 1;
      const int kbase = kt * 128;
      if (kt + 1 < ntiles) {                 // prefetch next tile (async)
#pragma unroll
        for (int t = 0; t < 4; ++t) {
          GLD16(ksrcT[t] + (long)(kbase + 128) * kHID, &Kt[cur ^ 1][wave * 2048 + t * 512]);
          GLD16(vsrcT[t] + kbase + 128, &Vt[cur ^ 1][wave * 2048 + t * 512]);
        }
      }
      // ---- QK^T (swapped): sacc[nb] = S[kp=kbase+nb*16+lh*4+r][q] ----
      const char* kb_ = (const char*)&Kt[cur][0];
      const int xa = ((lh ^ (lr & 7)) << 4);
      const int xb = (((4 + lh) ^ (lr & 7)) << 4);
      f32x4 sacc[8] = {};
      __builtin_amdgcn_s_setprio(1);
#pragma unroll
      for (int nb = 0; nb < 8; ++nb) {
        const int rowb = (nb * 16 + lr) * 128;
        const f16x8 kf0 = *reinterpret_cast<const f16x8*>(kb_ + rowb + xa);
        const f16x8 kf1 = *reinterpret_cast<const f16x8*>(kb_ + rowb + xb);
        sacc[nb] = __builtin_amdgcn_mfma_f32_16x16x32_f16(kf0, qf0, sacc[nb], 0, 0, 0);
        sacc[nb] = __builtin_amdgcn_mfma_f32_16x16x32_f16(kf1, qf1, sacc[nb], 0, 0, 0);
      }
      __builtin_amdgcn_s_setprio(0);

      const int q = qbase + wave * 16 + lr;
      const bool tilevalid = ((flags >> (2 * kt)) & 3u) == 3u;
      const bool fast = tilevalid && (kbase + 142 <= qbase);

      if (fast) {
        const float b31 = bias_sh[31];
        float pmax = sacc[0][0];
#pragma unroll
        for (int nb = 0; nb < 8; ++nb)
#pragma unroll
          for (int r = 0; r < 4; ++r) pmax = fmaxf(pmax, sacc[nb][r]);
        float mb = m - b31;
        if (!__all(pmax <= mb + 11.5416f)) {      // THR=8 nats in log2 units
          float tmax = fmaxf(pmax, __shfl_xor(pmax, 16, 64));
          tmax = fmaxf(tmax, __shfl_xor(tmax, 32, 64));
          const float mnew = fmaxf(m, tmax + b31);
          const float alpha = exp2f(m - mnew);    // m finite here (past tiles)
          lsum *= alpha;
          float alq[4];
#pragma unroll
          for (int r = 0; r < 4; ++r) alq[r] = __shfl(alpha, lh * 4 + r, 64);
#pragma unroll
          for (int nd = 0; nd < 4; ++nd) {
            acco[nd][0] *= alq[0]; acco[nd][1] *= alq[1];
            acco[nd][2] *= alq[2]; acco[nd][3] *= alq[3];
          }
          m = mnew;
          mb = m - b31;
        }
        float rs = 0.f;
#pragma unroll
        for (int nb = 0; nb < 8; ++nb)
#pragma unroll
          for (int r = 0; r < 4; ++r) {
            const float pv = exp2f(sacc[nb][r] - mb);
            sacc[nb][r] = pv;
            rs += pv;
          }
        rs += __shfl_xor(rs, 16, 64);
        rs += __shfl_xor(rs, 32, 64);
        lsum += rs;
      } else {
        float pmax = -INFINITY;
#pragma unroll
        for (int nb = 0; nb < 8; ++nb)
#pragma unroll
          for (int r = 0; r < 4; ++r) {
            const int kp = kbase + nb * 16 + lh * 4 + r;
            const float mbv = tilevalid ? 0.f : maskbias[b * kS + kp];
            int d = q - kp;
            d = d > 15 ? 15 : d;
            d = d < -16 ? -16 : d;
            const float s = sacc[nb][r] + bias_sh[d + 16] + mbv;
            sacc[nb][r] = (kp <= q) ? s : -INFINITY;
            pmax = fmaxf(pmax, sacc[nb][r]);
          }
        if (!__all(pmax <= m + 11.5416f)) {
          float tmax = fmaxf(pmax, __shfl_xor(pmax, 16, 64));
          tmax = fmaxf(tmax, __shfl_xor(tmax, 32, 64));
          const float mnew = fmaxf(m, tmax);
          const float alpha = (mnew == -INFINITY) ? 1.f : exp2f(m - mnew);
          lsum *= alpha;
          float alq[4];
#pragma unroll
          for (int r = 0; r < 4; ++r) alq[r] = __shfl(alpha, lh * 4 + r, 64);
#pragma unroll
          for (int nd = 0; nd < 4; ++nd) {
            acco[nd][0] *= alq[0]; acco[nd][1] *= alq[1];
            acco[nd][2] *= alq[2]; acco[nd][3] *= alq[3];
          }
          m = mnew;
        }
        float rs = 0.f;
#pragma unroll
        for (int nb = 0; nb < 8; ++nb)
#pragma unroll
          for (int r = 0; r < 4; ++r) {
            const float pv = (sacc[nb][r] == -INFINITY) ? 0.f : exp2f(sacc[nb][r] - m);
            sacc[nb][r] = pv;
            rs += pv;
          }
        rs += __shfl_xor(rs, 16, 64);
        rs += __shfl_xor(rs, 32, 64);
        lsum += rs;
      }

      // ---- pack P -> fp16 A-frags (validated shfl pattern) ----
      int pk[8][2];
#pragma unroll
      for (int nb = 0; nb < 8; ++nb) {
        pk[nb][0] = __builtin_bit_cast(int, __builtin_amdgcn_cvt_pkrtz(sacc[nb][0], sacc[nb][1]));
        pk[nb][1] = __builtin_bit_cast(int, __builtin_amdgcn_cvt_pkrtz(sacc[nb][2], sacc[nb][3]));
      }
      const int srcA = (((lh * 2) & 3) << 4) | lr;
      const int srcB = (((lh * 2 + 1) & 3) << 4) | lr;
      const bool lo = lh < 2;
      int4 wv[4];
#pragma unroll
      for (int s = 0; s < 4; ++s) {
        const int a0 = __shfl(pk[2 * s][0], srcA, 64), b0 = __shfl(pk[2 * s + 1][0], srcA, 64);
        const int a1 = __shfl(pk[2 * s][1], srcA, 64), b1 = __shfl(pk[2 * s + 1][1], srcA, 64);
        const int a2 = __shfl(pk[2 * s][0], srcB, 64), b2 = __shfl(pk[2 * s + 1][0], srcB, 64);
        const int a3 = __shfl(pk[2 * s][1], srcB, 64), b3 = __shfl(pk[2 * s + 1][1], srcB, 64);
        wv[s].x = lo ? a0 : b0; wv[s].y = lo ? a1 : b1;
        wv[s].z = lo ? a2 : b2; wv[s].w = lo ? a3 : b3;
      }
      // ---- PV from swizzled Vt ----
      const char* vb = (const char*)&Vt[cur][0];
      __builtin_amdgcn_s_setprio(1);
#pragma unroll
      for (int s = 0; s < 4; ++s) {
        const f16x8 pa = *reinterpret_cast<const f16x8*>(&wv[s]);
#pragma unroll
        for (int nd = 0; nd < 4; ++nd) {
          const int rowb = (nd * 16 + lr) * 256;
          const f16x8 bv = *reinterpret_cast<const f16x8*>(vb + rowb + ((((s * 4) + lh) ^ lr) << 4));
          acco[nd] = __builtin_amdgcn_mfma_f32_16x16x32_f16(pa, bv, acco[nd], 0, 0, 0);
        }
      }
      __builtin_amdgcn_s_setprio(0);
      __syncthreads();   // reads of cur done + prefetch drained
    }
    // ---- epilogue ----
    float lsq[4];
#pragma unroll
    for (int r = 0; r < 4; ++r) lsq[r] = __shfl(lsum, lh * 4 + r, 64);
#pragma unroll
    for (int nd = 0; nd < 4; ++nd)
#pragma unroll
      for (int r = 0; r < 4; ++r) {
        const float den = lsq[r];
        const float v = den > 0.f ? acco[nd][r] / den : 0.f;
        ctx[((long)b * kS + qbase + wave * 16 + lh * 4 + r) * kHID + h * 64 + nd * 16 + lr] =
            (_Float16)v;
      }
  }
}

// -------------------------------------------------------------- out GEMM ---
// 64x128 tile, 1D grid 512, XCD-clustered: bx = bid&7 (B-panel 256KB/XCD).
__global__ __launch_bounds__(256) void gemm_out(const _Float16* __restrict__ A,
                                                const _Float16* __restrict__ W,
                                                float* __restrict__ C,
                                                int M, int N, int K) {
  __shared__ __align__(16) _Float16 As[64 * 32];
  __shared__ __align__(16) _Float16 Bs[128 * 32];
  const int tid  = threadIdx.x;
  const int lane = tid & 63;
  const int wave = tid >> 6;
  const long bm = (long)(blockIdx.x >> 3) * 64;
  const long bn = (long)(blockIdx.x & 7) * 128;
  const int wr = (wave >> 1) * 32;
  const int wc = (wave & 1) * 64;

  const int srowA = wave * 16 + (lane >> 2);
  const int srowB = wave * 32 + (lane >> 2);
  const int scol = (lane & 3) * 8;
  const _Float16* ga = A + (bm + srowA) * (long)K + scol;
  const _Float16* gb = W + (bn + srowB) * (long)K + scol;
  _Float16* lA0 = &As[wave * 512];
  _Float16* lB0 = &Bs[wave * 1024];
  _Float16* lB1 = &Bs[wave * 1024 + 512];

  const int lr = lane & 15;
  const int lk = (lane >> 4) * 8;
  f32x4 acc[2][4] = {};

  for (int k0 = 0; k0 < K; k0 += 32) {
    GLD16(ga + k0, lA0);
    GLD16(gb + k0, lB0);
    GLD16(gb + k0 + 16 * (long)K, lB1);
    __syncthreads();
    f16x8 af[2], bf[4];
#pragma unroll
    for (int i = 0; i < 2; ++i)
      af[i] = *reinterpret_cast<const f16x8*>(&As[(wr + i * 16 + lr) * 32 + lk]);
#pragma unroll
    for (int j = 0; j < 4; ++j)
      bf[j] = *reinterpret_cast<const f16x8*>(&Bs[(wc + j * 16 + lr) * 32 + lk]);
#pragma unroll
    for (int i = 0; i < 2; ++i)
#pragma unroll
      for (int j = 0; j < 4; ++j)
        acc[i][j] = __builtin_amdgcn_mfma_f32_16x16x32_f16(af[i], bf[j], acc[i][j], 0, 0, 0);
    __syncthreads();
  }

  const int cr0 = wr + (lane >> 4) * 4;
  const int cc0 = wc + lr;
#pragma unroll
  for (int i = 0; i < 2; ++i)
#pragma unroll
    for (int j = 0; j < 4; ++j)
#pragma unroll
      for (int r = 0; r < 4; ++r)
        C[(bm + cr0 + i * 16 + r) * N + bn + cc0 + j * 16] = acc[i][j][r];
}

// ---------------------------------------------------------------- launch ----
extern "C" void kernel_launch(void* const* d_in, const int* in_sizes, int n_in,
                              void* d_out, int out_size, void* d_ws, size_t ws_size,
                              hipStream_t stream) {
  const float* x    = (const float*)d_in[0];
  const int*   mask = (const int*)d_in[1];
  const float* Wq   = (const float*)d_in[2];
  const float* Wk   = (const float*)d_in[3];
  const float* Wv   = (const float*)d_in[4];
  const float* Wo   = (const float*)d_in[5];
  const float* rel  = (const float*)d_in[6];
  float* out = (float*)d_out;

  const int M = kB * kS;          // 4096
  const int NX = M * kHID;        // 4,194,304
  const int NW = kHID * kHID;     // 1,048,576

  _Float16* ws   = (_Float16*)d_ws;
  _Float16* xh   = ws;
  _Float16* wqh  = xh + NX;       // wq,wk,wv,wo contiguous
  _Float16* woh  = wqh + 3 * NW;
  _Float16* Qh   = woh + NW;
  _Float16* Kh   = Qh + NX;
  _Float16* Vtg  = Kh + NX;       // [B][H][64][S] transposed V
  _Float16* ctxh = Vtg + NX;
  float*        maskbias  = (float*)(ctxh + NX);          // [B][S] f32
  unsigned int* tileflags = (unsigned int*)(maskbias + kB * kS);

  prep_all<<<2050, 256, 0, stream>>>(x, Wq, Wk, Wv, Wo, mask, xh, wqh,
                                     maskbias, tileflags);

  gemm_qkv<<<768, 256, 0, stream>>>(xh, wqh, Qh, Kh, Vtg);

  attn_fwd6<<<512, 256, 0, stream>>>(Qh, Kh, Vtg, maskbias, tileflags, rel, ctxh);

  gemm_out<<<512, 256, 0, stream>>>(ctxh, woh, out, M, kHID, kHID);
}

// Round 11
// 207.466 us; speedup vs baseline: 1.1892x; 1.1892x over previous
//
#include <hip/hip_runtime.h>
#include <math.h>

// T5Attention forward, MI355X/gfx950.  Round 10 (recovery, resubmit after
// infra timeout):
//   attn reverted to the proven round-7 kernel (VGPR=128, 57.6us):
//     KVBLK=128, swizzled global_load_lds dbuf, prefetch-at-top +
//     __syncthreads, swapped QK^T, defer-max THR=8, exp-domain softmax,
//     setprio, XCD clustering, q-pairs {i,31-i}
//   GEMMs keep XCD-clustered 1D grids (round 9, neutral)
//   HARD RULE for attn: VGPR must stay <= 128 (m69 cliff, verified twice)

typedef float    f32x4 __attribute__((ext_vector_type(4)));
typedef _Float16 f16x8 __attribute__((ext_vector_type(8)));
typedef _Float16 f16x4 __attribute__((ext_vector_type(4)));

#define GLD16(gp, lp) __builtin_amdgcn_global_load_lds(                       \
    (const __attribute__((address_space(1))) void*)(gp),                      \
    (__attribute__((address_space(3))) void*)(lp), 16, 0, 0)

static constexpr int kB   = 2;
static constexpr int kS   = 2048;
static constexpr int kHID = 1024;
static constexpr int kH   = 16;

// ------------------------------------------------------------ prep (fused) --
__global__ __launch_bounds__(256) void prep_all(const float* __restrict__ x,
                                                const float* __restrict__ w0,
                                                const float* __restrict__ w1,
                                                const float* __restrict__ w2,
                                                const float* __restrict__ w3,
                                                const int* __restrict__ maskp,
                                                _Float16* __restrict__ xh,
                                                _Float16* __restrict__ wh,
                                                float* __restrict__ maskbias,
                                                unsigned int* __restrict__ tileflags) {
  const int bid = blockIdx.x, tid = threadIdx.x;
  if (bid < 2048) {
    const float* src;
    _Float16* dst;
    int base;
    if (bid < 1024) {
      src = x; dst = xh; base = bid * 4096;
    } else {
      const int wsel = (bid - 1024) >> 8;
      src = wsel == 0 ? w0 : wsel == 1 ? w1 : wsel == 2 ? w2 : w3;
      dst = wh + (long)wsel * 1048576;
      base = ((bid - 1024) & 255) * 4096;
    }
#pragma unroll
    for (int it = 0; it < 4; ++it) {
      const int i = base + it * 1024 + tid * 4;
      const float4 v = *reinterpret_cast<const float4*>(src + i);
      f16x4 o;
      o[0] = (_Float16)v.x; o[1] = (_Float16)v.y;
      o[2] = (_Float16)v.z; o[3] = (_Float16)v.w;
      *reinterpret_cast<f16x4*>(dst + i) = o;
    }
  } else {
    const int b = bid - 2048;
    const int wave = tid >> 6, lane = tid & 63;
    __shared__ unsigned int partial[4];
    unsigned int mybits = 0;
#pragma unroll
    for (int it = 0; it < 8; ++it) {
      const int t = it * 4 + wave;
      const int kp = t * 64 + lane;
      const int mv = maskp[b * kS + kp];
      maskbias[b * kS + kp] = mv ? 0.f : -INFINITY;
      const unsigned long long bal = __ballot(mv != 0);
      if (bal == ~0ull) mybits |= (1u << t);
    }
    if (lane == 0) partial[wave] = mybits;
    __syncthreads();
    if (tid == 0) tileflags[b] = partial[0] | partial[1] | partial[2] | partial[3];
  }
}

// ------------------------------------------------------- fused QKV GEMM ----
// 1D grid 768, XCD-clustered: xcd x=bid&7 owns bx in [x*3,x*3+3).
__global__ __launch_bounds__(256) void gemm_qkv(const _Float16* __restrict__ A,
                                                const _Float16* __restrict__ W,
                                                _Float16* __restrict__ Qh,
                                                _Float16* __restrict__ Kh,
                                                _Float16* __restrict__ Vtg) {
  constexpr int K = kHID;
  __shared__ __align__(16) _Float16 As[128 * 32];
  __shared__ __align__(16) _Float16 Bs[128 * 32];
  const int tid  = threadIdx.x;
  const int lane = tid & 63;
  const int wave = tid >> 6;
  const int xcd = blockIdx.x & 7, l = blockIdx.x >> 3;
  const long bm = (long)(l & 31) * 128;             // by = l%32
  const long bn = (long)(xcd * 3 + (l >> 5)) * 128; // bx = xcd*3 + l/32
  const int wr = (wave >> 1) * 64;
  const int wc = (wave & 1) * 64;

  const int srow = wave * 32 + (lane >> 2);
  const int scol = (lane & 3) * 8;
  const _Float16* ga = A + (bm + srow) * (long)K + scol;
  const _Float16* gb = W + (bn + srow) * (long)K + scol;
  _Float16* lA0 = &As[wave * 1024];
  _Float16* lA1 = &As[wave * 1024 + 512];
  _Float16* lB0 = &Bs[wave * 1024];
  _Float16* lB1 = &Bs[wave * 1024 + 512];

  const int lr = lane & 15;
  const int lk = (lane >> 4) * 8;
  f32x4 acc[4][4] = {};

  for (int k0 = 0; k0 < K; k0 += 32) {
    GLD16(ga + k0, lA0);
    GLD16(ga + k0 + 16 * (long)K, lA1);
    GLD16(gb + k0, lB0);
    GLD16(gb + k0 + 16 * (long)K, lB1);
    __syncthreads();
    f16x8 af[4], bf[4];
#pragma unroll
    for (int i = 0; i < 4; ++i) {
      af[i] = *reinterpret_cast<const f16x8*>(&As[(wr + i * 16 + lr) * 32 + lk]);
      bf[i] = *reinterpret_cast<const f16x8*>(&Bs[(wc + i * 16 + lr) * 32 + lk]);
    }
#pragma unroll
    for (int i = 0; i < 4; ++i)
#pragma unroll
      for (int j = 0; j < 4; ++j)
        acc[i][j] = __builtin_amdgcn_mfma_f32_16x16x32_f16(af[i], bf[j], acc[i][j], 0, 0, 0);
    __syncthreads();
  }

  const int cr0 = wr + (lane >> 4) * 4;
  const int cc0 = wc + lr;
  const int cb = (int)(bn >> 10);          // 0=Q 1=K 2=V (block-uniform)
#pragma unroll
  for (int i = 0; i < 4; ++i)
#pragma unroll
    for (int j = 0; j < 4; ++j)
#pragma unroll
      for (int r = 0; r < 4; ++r) {
        const long row = bm + cr0 + i * 16 + r;       // token index
        const int  col = (int)bn + cc0 + j * 16;      // 0..3071
        const float v = acc[i][j][r];
        if (cb == 0) {
          Qh[row * kHID + col] = (_Float16)(v * 0.125f);
        } else if (cb == 1) {
          Kh[row * kHID + (col - 1024)] = (_Float16)v;
        } else {
          const int hid = col - 2048;
          const int hh = hid >> 6, dd = hid & 63;
          const int bb = (int)(row >> 11), sp = (int)(row & 2047);
          Vtg[((long)(bb * kH + hh) * 64 + dd) * kS + sp] = (_Float16)v;
        }
      }
}

// ---------------------------------------------------------- flash attention -
// Round-7 kernel, verbatim (VGPR=128 proven).  1D grid 512, block 256.
// KVBLK=128, XCD-clustered, q-pairs {i,31-i} -> uniform 17 tiles/block.
__global__ __launch_bounds__(256) void attn_fwd4(const _Float16* __restrict__ Qh,
                                                 const _Float16* __restrict__ Kh,
                                                 const _Float16* __restrict__ Vtg,
                                                 const float* __restrict__ maskbias,
                                                 const unsigned int* __restrict__ tileflags,
                                                 const float* __restrict__ rel_emb,
                                                 _Float16* __restrict__ ctx) {
  __shared__ __align__(16) _Float16 Kt[2][128 * 64];
  __shared__ __align__(16) _Float16 Vt[2][64 * 128];
  __shared__ float bias_sh[32];

  const int tid  = threadIdx.x;
  const int lane = tid & 63;
  const int wave = tid >> 6;
  const int o = blockIdx.x;
  const int slot = o >> 3;
  const int p_ = (o & 7) + 8 * (slot >> 4);   // (b,h) group 0..31
  const int qp = slot & 15;                   // q pair 0..15
  const int b = p_ >> 4, h = p_ & 15;

  const int lr = lane & 15;
  const int lh = lane >> 4;

  if (tid < 32) bias_sh[tid] = rel_emb[tid * kH + h];
  const unsigned int flags = tileflags[b];

  // K staging (inst t=0..3): lane l -> LDS row wave*32+t*8+(l>>3), chunk l&7.
  const int kro = wave * 32 + (lane >> 3);
  const int kch = ((lane & 7) ^ (lane >> 3)) * 8;
  const _Float16* ksrcT[4];
#pragma unroll
  for (int t = 0; t < 4; ++t)
    ksrcT[t] = Kh + ((long)b * kS + kro + t * 8) * kHID + h * 64 + kch;
  // V staging (inst t=0..3): lane l -> LDS row wave*16+t*4+(l>>4), chunk l&15.
  const long bh64 = (long)(b * kH + h) * 64;
  const _Float16* vsrcT[4];
#pragma unroll
  for (int t = 0; t < 4; ++t) {
    const int d = wave * 16 + t * 4 + (lane >> 4);
    const int c = (lane & 15) ^ (d & 15);
    vsrcT[t] = Vtg + (bh64 + d) * kS + c * 8;
  }

  __syncthreads();  // bias_sh visible before first use

  for (int pass = 0; pass < 2; ++pass) {
    const int qt = (pass == 0) ? qp : 31 - qp;
    const int qbase = qt * 64;

    const long qrow = (long)b * kS + qbase + wave * 16 + lr;
    const f16x8 qf0 = *reinterpret_cast<const f16x8*>(&Qh[qrow * kHID + h * 64 + lh * 8]);
    const f16x8 qf1 = *reinterpret_cast<const f16x8*>(&Qh[qrow * kHID + h * 64 + 32 + lh * 8]);

    float m = -INFINITY, lsum = 0.f;
    f32x4 acco[4] = {};

    // prologue: stage tile 0 -> buf 0
#pragma unroll
    for (int t = 0; t < 4; ++t) {
      GLD16(ksrcT[t], &Kt[0][wave * 2048 + t * 512]);
      GLD16(vsrcT[t], &Vt[0][wave * 2048 + t * 512]);
    }
    __syncthreads();

    const int ntiles = (qt >> 1) + 1;
    for (int kt = 0; kt < ntiles; ++kt) {
      const int cur = kt & 1;
      const int kbase = kt * 128;
      if (kt + 1 < ntiles) {                 // prefetch next tile (async)
#pragma unroll
        for (int t = 0; t < 4; ++t) {
          GLD16(ksrcT[t] + (long)(kbase + 128) * kHID, &Kt[cur ^ 1][wave * 2048 + t * 512]);
          GLD16(vsrcT[t] + kbase + 128, &Vt[cur ^ 1][wave * 2048 + t * 512]);
        }
      }
      // ---- QK^T (swapped): sacc[nb] = S[kp=kbase+nb*16+lh*4+r][q] ----
      const char* kb_ = (const char*)&Kt[cur][0];
      const int xa = ((lh ^ (lr & 7)) << 4);
      const int xb = (((4 + lh) ^ (lr & 7)) << 4);
      f32x4 sacc[8] = {};
      __builtin_amdgcn_s_setprio(1);
#pragma unroll
      for (int nb = 0; nb < 8; ++nb) {
        const int rowb = (nb * 16 + lr) * 128;
        const f16x8 kf0 = *reinterpret_cast<const f16x8*>(kb_ + rowb + xa);
        const f16x8 kf1 = *reinterpret_cast<const f16x8*>(kb_ + rowb + xb);
        sacc[nb] = __builtin_amdgcn_mfma_f32_16x16x32_f16(kf0, qf0, sacc[nb], 0, 0, 0);
        sacc[nb] = __builtin_amdgcn_mfma_f32_16x16x32_f16(kf1, qf1, sacc[nb], 0, 0, 0);
      }
      __builtin_amdgcn_s_setprio(0);

      const int q = qbase + wave * 16 + lr;
      const bool tilevalid = ((flags >> (2 * kt)) & 3u) == 3u;
      const bool fast = tilevalid && (kbase + 142 <= qbase);

      if (fast) {
        const float b31 = bias_sh[31];
        float pmax = sacc[0][0];
#pragma unroll
        for (int nb = 0; nb < 8; ++nb)
#pragma unroll
          for (int r = 0; r < 4; ++r) pmax = fmaxf(pmax, sacc[nb][r]);
        float mb = m - b31;
        if (!__all(pmax <= mb + 8.f)) {
          float tmax = fmaxf(pmax, __shfl_xor(pmax, 16, 64));
          tmax = fmaxf(tmax, __shfl_xor(tmax, 32, 64));
          const float mnew = fmaxf(m, tmax + b31);
          const float alpha = __expf(m - mnew);     // m finite here (past tiles)
          lsum *= alpha;
          float alq[4];
#pragma unroll
          for (int r = 0; r < 4; ++r) alq[r] = __shfl(alpha, lh * 4 + r, 64);
#pragma unroll
          for (int nd = 0; nd < 4; ++nd) {
            acco[nd][0] *= alq[0]; acco[nd][1] *= alq[1];
            acco[nd][2] *= alq[2]; acco[nd][3] *= alq[3];
          }
          m = mnew;
          mb = m - b31;
        }
        float rs = 0.f;
#pragma unroll
        for (int nb = 0; nb < 8; ++nb)
#pragma unroll
          for (int r = 0; r < 4; ++r) {
            const float pv = __expf(sacc[nb][r] - mb);
            sacc[nb][r] = pv;
            rs += pv;
          }
        rs += __shfl_xor(rs, 16, 64);
        rs += __shfl_xor(rs, 32, 64);
        lsum += rs;
      } else {
        float pmax = -INFINITY;
#pragma unroll
        for (int nb = 0; nb < 8; ++nb)
#pragma unroll
          for (int r = 0; r < 4; ++r) {
            const int kp = kbase + nb * 16 + lh * 4 + r;
            const float mbv = tilevalid ? 0.f : maskbias[b * kS + kp];
            int d = q - kp;
            d = d > 15 ? 15 : d;
            d = d < -16 ? -16 : d;
            const float s = sacc[nb][r] + bias_sh[d + 16] + mbv;
            sacc[nb][r] = (kp <= q) ? s : -INFINITY;
            pmax = fmaxf(pmax, sacc[nb][r]);
          }
        if (!__all(pmax <= m + 8.f)) {
          float tmax = fmaxf(pmax, __shfl_xor(pmax, 16, 64));
          tmax = fmaxf(tmax, __shfl_xor(tmax, 32, 64));
          const float mnew = fmaxf(m, tmax);
          const float alpha = (mnew == -INFINITY) ? 1.f : __expf(m - mnew);
          lsum *= alpha;
          float alq[4];
#pragma unroll
          for (int r = 0; r < 4; ++r) alq[r] = __shfl(alpha, lh * 4 + r, 64);
#pragma unroll
          for (int nd = 0; nd < 4; ++nd) {
            acco[nd][0] *= alq[0]; acco[nd][1] *= alq[1];
            acco[nd][2] *= alq[2]; acco[nd][3] *= alq[3];
          }
          m = mnew;
        }
        float rs = 0.f;
#pragma unroll
        for (int nb = 0; nb < 8; ++nb)
#pragma unroll
          for (int r = 0; r < 4; ++r) {
            const float pv = (sacc[nb][r] == -INFINITY) ? 0.f : __expf(sacc[nb][r] - m);
            sacc[nb][r] = pv;
            rs += pv;
          }
        rs += __shfl_xor(rs, 16, 64);
        rs += __shfl_xor(rs, 32, 64);
        lsum += rs;
      }

      // ---- pack P -> fp16 A-frags (validated shfl pattern) ----
      int pk[8][2];
#pragma unroll
      for (int nb = 0; nb < 8; ++nb) {
        pk[nb][0] = __builtin_bit_cast(int, __builtin_amdgcn_cvt_pkrtz(sacc[nb][0], sacc[nb][1]));
        pk[nb][1] = __builtin_bit_cast(int, __builtin_amdgcn_cvt_pkrtz(sacc[nb][2], sacc[nb][3]));
      }
      const int srcA = (((lh * 2) & 3) << 4) | lr;
      const int srcB = (((lh * 2 + 1) & 3) << 4) | lr;
      const bool lo = lh < 2;
      int4 wv[4];
#pragma unroll
      for (int s = 0; s < 4; ++s) {
        const int a0 = __shfl(pk[2 * s][0], srcA, 64), b0 = __shfl(pk[2 * s + 1][0], srcA, 64);
        const int a1 = __shfl(pk[2 * s][1], srcA, 64), b1 = __shfl(pk[2 * s + 1][1], srcA, 64);
        const int a2 = __shfl(pk[2 * s][0], srcB, 64), b2 = __shfl(pk[2 * s + 1][0], srcB, 64);
        const int a3 = __shfl(pk[2 * s][1], srcB, 64), b3 = __shfl(pk[2 * s + 1][1], srcB, 64);
        wv[s].x = lo ? a0 : b0; wv[s].y = lo ? a1 : b1;
        wv[s].z = lo ? a2 : b2; wv[s].w = lo ? a3 : b3;
      }
      // ---- PV from swizzled Vt ----
      const char* vb = (const char*)&Vt[cur][0];
      __builtin_amdgcn_s_setprio(1);
#pragma unroll
      for (int s = 0; s < 4; ++s) {
        const f16x8 pa = *reinterpret_cast<const f16x8*>(&wv[s]);
#pragma unroll
        for (int nd = 0; nd < 4; ++nd) {
          const int rowb = (nd * 16 + lr) * 256;
          const f16x8 bv = *reinterpret_cast<const f16x8*>(vb + rowb + ((((s * 4) + lh) ^ lr) << 4));
          acco[nd] = __builtin_amdgcn_mfma_f32_16x16x32_f16(pa, bv, acco[nd], 0, 0, 0);
        }
      }
      __builtin_amdgcn_s_setprio(0);
      __syncthreads();   // reads of cur done + prefetch drained
    }
    // ---- epilogue ----
    float lsq[4];
#pragma unroll
    for (int r = 0; r < 4; ++r) lsq[r] = __shfl(lsum, lh * 4 + r, 64);
#pragma unroll
    for (int nd = 0; nd < 4; ++nd)
#pragma unroll
      for (int r = 0; r < 4; ++r) {
        const float den = lsq[r];
        const float v = den > 0.f ? acco[nd][r] / den : 0.f;
        ctx[((long)b * kS + qbase + wave * 16 + lh * 4 + r) * kHID + h * 64 + nd * 16 + lr] =
            (_Float16)v;
      }
  }
}

// -------------------------------------------------------------- out GEMM ---
// 64x128 tile, 1D grid 512, XCD-clustered: bx = bid&7.
__global__ __launch_bounds__(256) void gemm_out(const _Float16* __restrict__ A,
                                                const _Float16* __restrict__ W,
                                                float* __restrict__ C,
                                                int M, int N, int K) {
  __shared__ __align__(16) _Float16 As[64 * 32];
  __shared__ __align__(16) _Float16 Bs[128 * 32];
  const int tid  = threadIdx.x;
  const int lane = tid & 63;
  const int wave = tid >> 6;
  const long bm = (long)(blockIdx.x >> 3) * 64;
  const long bn = (long)(blockIdx.x & 7) * 128;
  const int wr = (wave >> 1) * 32;
  const int wc = (wave & 1) * 64;

  const int srowA = wave * 16 + (lane >> 2);
  const int srowB = wave * 32 + (lane >> 2);
  const int scol = (lane & 3) * 8;
  const _Float16* ga = A + (bm + srowA) * (long)K + scol;
  const _Float16* gb = W + (bn + srowB) * (long)K + scol;
  _Float16* lA0 = &As[wave * 512];
  _Float16* lB0 = &Bs[wave * 1024];
  _Float16* lB1 = &Bs[wave * 1024 + 512];

  const int lr = lane & 15;
  const int lk = (lane >> 4) * 8;
  f32x4 acc[2][4] = {};

  for (int k0 = 0; k0 < K; k0 += 32) {
    GLD16(ga + k0, lA0);
    GLD16(gb + k0, lB0);
    GLD16(gb + k0 + 16 * (long)K, lB1);
    __syncthreads();
    f16x8 af[2], bf[4];
#pragma unroll
    for (int i = 0; i < 2; ++i)
      af[i] = *reinterpret_cast<const f16x8*>(&As[(wr + i * 16 + lr) * 32 + lk]);
#pragma unroll
    for (int j = 0; j < 4; ++j)
      bf[j] = *reinterpret_cast<const f16x8*>(&Bs[(wc + j * 16 + lr) * 32 + lk]);
#pragma unroll
    for (int i = 0; i < 2; ++i)
#pragma unroll
      for (int j = 0; j < 4; ++j)
        acc[i][j] = __builtin_amdgcn_mfma_f32_16x16x32_f16(af[i], bf[j], acc[i][j], 0, 0, 0);
    __syncthreads();
  }

  const int cr0 = wr + (lane >> 4) * 4;
  const int cc0 = wc + lr;
#pragma unroll
  for (int i = 0; i < 2; ++i)
#pragma unroll
    for (int j = 0; j < 4; ++j)
#pragma unroll
      for (int r = 0; r < 4; ++r)
        C[(bm + cr0 + i * 16 + r) * N + bn + cc0 + j * 16] = acc[i][j][r];
}

// ---------------------------------------------------------------- launch ----
extern "C" void kernel_launch(void* const* d_in, const int* in_sizes, int n_in,
                              void* d_out, int out_size, void* d_ws, size_t ws_size,
                              hipStream_t stream) {
  const float* x    = (const float*)d_in[0];
  const int*   mask = (const int*)d_in[1];
  const float* Wq   = (const float*)d_in[2];
  const float* Wk   = (const float*)d_in[3];
  const float* Wv   = (const float*)d_in[4];
  const float* Wo   = (const float*)d_in[5];
  const float* rel  = (const float*)d_in[6];
  float* out = (float*)d_out;

  const int M = kB * kS;          // 4096
  const int NX = M * kHID;        // 4,194,304
  const int NW = kHID * kHID;     // 1,048,576

  _Float16* ws   = (_Float16*)d_ws;
  _Float16* xh   = ws;
  _Float16* wqh  = xh + NX;       // wq,wk,wv,wo contiguous
  _Float16* woh  = wqh + 3 * NW;
  _Float16* Qh   = woh + NW;
  _Float16* Kh   = Qh + NX;
  _Float16* Vtg  = Kh + NX;       // [B][H][64][S] transposed V
  _Float16* ctxh = Vtg + NX;
  float*        maskbias  = (float*)(ctxh + NX);          // [B][S] f32
  unsigned int* tileflags = (unsigned int*)(maskbias + kB * kS);

  prep_all<<<2050, 256, 0, stream>>>(x, Wq, Wk, Wv, Wo, mask, xh, wqh,
                                     maskbias, tileflags);

  gemm_qkv<<<768, 256, 0, stream>>>(xh, wqh, Qh, Kh, Vtg);

  attn_fwd4<<<512, 256, 0, stream>>>(Qh, Kh, Vtg, maskbias, tileflags, rel, ctxh);

  gemm_out<<<512, 256, 0, stream>>>(ctxh, woh, out, M, kHID, kHID);
}